// Round 1
// baseline (221.917 us; speedup 1.0000x reference)
//
#include <hip/hip_runtime.h>
#include <math.h>

#define N_REF   50000
#define BATCH   16
#define KDIM    4096          // 32*128
#define CHUNK   256           // k-chunk in floats (1 KiB LDS row per b)
#define NCHUNK  (KDIM / CHUNK) // 16
#define RPB     16            // n-rows per block
#define RPW     4             // n-rows per wave

// K1: dist'[b,n] = r2[n] - 2*dot(x[b], raw[n])   (x2[b] dropped: softmax-invariant)
__global__ __launch_bounds__(256) void dist_kernel(const float* __restrict__ x,
                                                   const float* __restrict__ raw,
                                                   float* __restrict__ dist)
{
    __shared__ float xs[BATCH * CHUNK];   // 16 KiB
    const int tid  = threadIdx.x;
    const int lane = tid & 63;
    const int wv   = tid >> 6;            // 0..3
    const long n_base = (long)blockIdx.x * RPB + wv * RPW;

    float acc[BATCH][RPW];
    #pragma unroll
    for (int b = 0; b < BATCH; ++b)
        #pragma unroll
        for (int r = 0; r < RPW; ++r) acc[b][r] = 0.f;
    float r2a[RPW] = {0.f, 0.f, 0.f, 0.f};

    for (int c = 0; c < NCHUNK; ++c) {
        __syncthreads();   // previous chunk's LDS reads done before overwrite
        // stage x[:, c*256 : c*256+256] -> LDS, 1024 float4, 4 per thread, coalesced
        #pragma unroll
        for (int i = 0; i < 4; ++i) {
            const int slot = i * 256 + tid;      // 0..1023
            const int b = slot >> 6;
            const int f = slot & 63;
            const float4 v = *(const float4*)(x + (size_t)b * KDIM + (size_t)c * CHUNK + f * 4);
            *(float4*)(xs + b * CHUNK + f * 4) = v;
        }
        __syncthreads();

        // HBM stream: 4 rows x float4, coalesced 1KB per wave instruction
        float4 rv[RPW];
        #pragma unroll
        for (int r = 0; r < RPW; ++r) {
            rv[r] = *(const float4*)(raw + (size_t)(n_base + r) * KDIM
                                         + (size_t)c * CHUNK + lane * 4);
            r2a[r] = fmaf(rv[r].x, rv[r].x, r2a[r]);
            r2a[r] = fmaf(rv[r].y, rv[r].y, r2a[r]);
            r2a[r] = fmaf(rv[r].z, rv[r].z, r2a[r]);
            r2a[r] = fmaf(rv[r].w, rv[r].w, r2a[r]);
        }
        // x register reuse across the 4 rows: 16 ds_read_b128 per chunk per lane
        #pragma unroll
        for (int b = 0; b < BATCH; ++b) {
            const float4 xv = *(const float4*)(xs + b * CHUNK + lane * 4);
            #pragma unroll
            for (int r = 0; r < RPW; ++r) {
                acc[b][r] = fmaf(rv[r].x, xv.x, acc[b][r]);
                acc[b][r] = fmaf(rv[r].y, xv.y, acc[b][r]);
                acc[b][r] = fmaf(rv[r].z, xv.z, acc[b][r]);
                acc[b][r] = fmaf(rv[r].w, xv.w, acc[b][r]);
            }
        }
    }

    // Cross-lane reduce of 64 accumulators: value v = b*4+r ends (summed) on lane v.
    // Log2 exchange tree: 63 shfl+add total per lane, all indices compile-time.
    float vals[64];
    #pragma unroll
    for (int b = 0; b < BATCH; ++b)
        #pragma unroll
        for (int r = 0; r < RPW; ++r) vals[b * RPW + r] = acc[b][r];

    #pragma unroll
    for (int k = 0; k < 6; ++k) {
        const int bit = 1 << k;
        const bool hi = (lane & bit) != 0;
        #pragma unroll
        for (int i = 0; i < (64 >> (k + 1)); ++i) {
            const float a  = vals[2 * i];
            const float bb = vals[2 * i + 1];
            const float keep = hi ? bb : a;
            const float send = hi ? a  : bb;
            const float recv = __shfl_xor(send, bit, 64);
            vals[i] = keep + recv;   // in-place safe: writes at i, reads at >= 2i
        }
    }

    // r2: broadcast-reduce the 4 row sums to all lanes
    #pragma unroll
    for (int r = 0; r < RPW; ++r) {
        #pragma unroll
        for (int k = 0; k < 6; ++k)
            r2a[r] += __shfl_xor(r2a[r], 1 << k, 64);
    }

    const int b_out = lane >> 2;
    const int r_out = lane & 3;
    const float r2v = (r_out == 0) ? r2a[0] : (r_out == 1) ? r2a[1]
                    : (r_out == 2) ? r2a[2] : r2a[3];
    dist[(size_t)b_out * N_REF + (size_t)(n_base + r_out)] = r2v - 2.0f * vals[0];
}

// K2: in-place softmax over each row of d_out[16][50000]
__global__ __launch_bounds__(1024) void softmax_kernel(float* __restrict__ d)
{
    const int b = blockIdx.x;
    float* row = d + (size_t)b * N_REF;
    const int tid = threadIdx.x;

    // branchless online (m, s)
    float m = -INFINITY, s = 0.f;
    for (int n = tid; n < N_REF; n += 1024) {
        const float v = row[n];
        const float M = fmaxf(m, v);
        s = s * __expf(m - M) + __expf(v - M);
        m = M;
    }
    // wave merge
    #pragma unroll
    for (int k = 1; k < 64; k <<= 1) {
        const float mo = __shfl_xor(m, k, 64);
        const float so = __shfl_xor(s, k, 64);
        const float M  = fmaxf(m, mo);
        s = s * __expf(m - M) + so * __expf(mo - M);
        m = M;
    }
    __shared__ float ms[16], ss[16];
    const int wv = tid >> 6, lane = tid & 63;
    if (lane == 0) { ms[wv] = m; ss[wv] = s; }
    __syncthreads();
    if (tid == 0) {
        float M = ms[0], S = ss[0];
        for (int i = 1; i < 16; ++i) {
            const float M2 = fmaxf(M, ms[i]);
            S = S * __expf(M - M2) + ss[i] * __expf(ms[i] - M2);
            M = M2;
        }
        ms[0] = M; ss[0] = 1.f / S;
    }
    __syncthreads();
    const float M = ms[0], Sinv = ss[0];
    for (int n = tid; n < N_REF; n += 1024)
        row[n] = __expf(row[n] - M) * Sinv;
}

extern "C" void kernel_launch(void* const* d_in, const int* in_sizes, int n_in,
                              void* d_out, int out_size, void* d_ws, size_t ws_size,
                              hipStream_t stream) {
    const float* x   = (const float*)d_in[0];   // [16][32][128]
    const float* raw = (const float*)d_in[1];   // [50000][32][128]
    float* out = (float*)d_out;                 // [16][50000]

    dist_kernel<<<N_REF / RPB, 256, 0, stream>>>(x, raw, out);
    softmax_kernel<<<BATCH, 1024, 0, stream>>>(out);
}